// Round 8
// baseline (132.158 us; speedup 1.0000x reference)
//
#include <hip/hip_runtime.h>

// Duration-based length regulation. B=8, T=512, D=512, MAX_LEN = T*15 = 7680.
// features fp32 (B,T,D), durations int32 (B,T), out fp32 (B,MAX_LEN,D).
//
// R15: branch-free constant-length store stream. R7 post-mortem: balance
// was neutral (third structural null) -> residual is per-store loop
// overhead (runtime trip counts, unpipelineable) and scan-prologue ramp at
// 4 blocks/CU. Now PPB=2 (2048 blocks, 8/CU), one phoneme per 128-lane
// sub, and a fully-unrolled 15-iteration select-addressed store loop:
// row = k<n ? start+k : z0+(k-n); val = k<n ? v : 0. Every thread issues
// exactly 15 branch-free stores. Ballast partition (R7, verified exact)
// carries over: block i zero-fills 30-sum2_i rows at total + 30i - st0_i.
#define BB 8
#define TT 512
#define DD 512
#define MAX_LEN 7680
#define PPB 2                         // phonemes per block
#define BPB (TT / PPB)                // 256 blocks per batch
#define QPB (PPB * 15)                // rows stored per block (30)
#define QPS 15                        // rows stored per 128-lane sub

__global__ __launch_bounds__(256) void regulate_kernel(
    const float4* __restrict__ feat,   // (B, T, DD/4)
    const int*    __restrict__ dur,    // (B, T)
    float4*       __restrict__ out)    // (B, MAX_LEN, DD/4)
{
    const int t    = threadIdx.x;
    const int blk  = blockIdx.x & (BPB - 1);   // block within batch
    const int b    = blockIdx.x >> 8;          // batch (BPB = 256)
    const int lane = t & 127;                  // float4 column in 2 KB row
    const int sub  = t >> 7;                   // owns phoneme 2*blk + sub
    const int l    = t & 63;                   // scan lane within wave

    // ---- issue ALL global loads up front (durations, then the row) ----
    const int4* d4p = (const int4*)(dur + b * TT + 8 * l);
    int4 da = d4p[0];
    int4 db = d4p[1];

    // this sub's feature row: address is STATIC (no scan needed)
    const int ph = PPB * blk + sub;
    const float4* featb = feat + (size_t)b * TT * (DD / 4) + lane;
    float4 v = featb[(size_t)ph * (DD / 4)];

    // ---- wave shfl scan over 512 clamped durations (verified R6/R7) ----
    int d[8] = {da.x, da.y, da.z, da.w, db.x, db.y, db.z, db.w};
    int s[8];
    int run = 0;
#pragma unroll
    for (int i = 0; i < 8; ++i) {
        int di = d[i] < 1 ? 1 : d[i];          // clamp(min=1)
        run += di;
        s[i] = run;                            // in-lane inclusive scan
    }
    int incl = run;
#pragma unroll
    for (int off = 1; off < 64; off <<= 1) {
        int vv = __shfl_up(incl, off, 64);
        if (l >= off) incl += vv;
    }
    const int pre = incl - run;                // exclusive prefix of lane

    // block's 2 phonemes (2blk, 2blk+1) live in lane L at pair offset jj
    const int L  = blk >> 2;
    const int jj = blk & 3;
    int t0 = __shfl(s[0], L, 64), t1 = __shfl(s[1], L, 64),
        t2 = __shfl(s[2], L, 64), t3 = __shfl(s[3], L, 64),
        t4 = __shfl(s[4], L, 64), t5 = __shfl(s[5], L, 64),
        t6 = __shfl(s[6], L, 64), t7 = __shfl(s[7], L, 64);
    int tm1, ta, tb;                           // s[2jj-1] (0 if jj=0), s[2jj], s[2jj+1]
    if      (jj == 0) { tm1 = 0;  ta = t0; tb = t1; }
    else if (jj == 1) { tm1 = t1; ta = t2; tb = t3; }
    else if (jj == 2) { tm1 = t3; ta = t4; tb = t5; }
    else              { tm1 = t5; ta = t6; tb = t7; }

    const int preL  = __shfl(pre, L, 64);
    const int total = __shfl(incl, 63, 64);    // cum[511]

    const int st0 = preL + tm1;                // start frame of phoneme 2blk
    const int d0  = ta - tm1;                  // duration of phoneme 2blk
    const int d1  = tb - ta;                   // duration of phoneme 2blk+1

    // ballast: block zero-fills QPB - (d0+d1) rows starting at P (exact tiling)
    const int P = total + QPB * blk - st0;

    int start, n, z0;
    if (sub == 0) { start = st0;      n = d0; z0 = P; }
    else          { start = st0 + d0; n = d1; z0 = P + (QPS - d0); }

    // ---- branch-free constant-length store stream: exactly 15 stores ----
    float4* outb = out + (size_t)b * MAX_LEN * (DD / 4) + lane;
    const float4 zero = make_float4(0.f, 0.f, 0.f, 0.f);
#pragma unroll
    for (int k = 0; k < QPS; ++k) {
        const bool real = k < n;
        const int  row  = real ? (start + k) : (z0 + (k - n));
        const float4 w  = real ? v : zero;
        outb[(size_t)row * (DD / 4)] = w;
    }
}

extern "C" void kernel_launch(void* const* d_in, const int* in_sizes, int n_in,
                              void* d_out, int out_size, void* d_ws, size_t ws_size,
                              hipStream_t stream) {
    // Select pointers by element count (features = B*T*D = 2097152, dur = 4096)
    const float* feat;
    const int*   dur;
    if (in_sizes[0] == BB * TT) {
        dur  = (const int*)d_in[0];
        feat = (const float*)d_in[1];
    } else {
        feat = (const float*)d_in[0];
        dur  = (const int*)d_in[1];
    }
    float* out = (float*)d_out;        // (B, MAX_LEN, D) fp32

    regulate_kernel<<<BB * BPB, 256, 0, stream>>>(
        (const float4*)feat, dur, (float4*)out);
}

// Round 9
// 130.329 us; speedup vs baseline: 1.0140x; 1.0140x over previous
//
#include <hip/hip_runtime.h>

// Duration-based length regulation. B=8, T=512, D=512, MAX_LEN = T*15 = 7680.
// features fp32 (B,T,D), durations int32 (B,T), out fp32 (B,MAX_LEN,D).
//
// R16: revert to best-measured variant (R12/R6, 130.72 us). Post-mortem
// history: binary-search removal (null), scan removal (null), ballast
// balancing (null), branch-free stores (-1.5us). Kernel ~30us vs ~21us
// arithmetic floor; measured region is dominated by ~95us of harness
// poison fills (503MB ws + 126MB out) visible in rocprof. Structure:
// phoneme-parallel scatter — each block owns 4 phonemes, feature-row load
// addresses are static (issued at cycle 0, hidden under the shfl scan),
// store streams carry zero loads. Padding zero-stored in even slices.
#define BB 8
#define TT 512
#define DD 512
#define MAX_LEN 7680
#define PPB 4                         // phonemes per block
#define BPB (TT / PPB)                // 128 blocks per batch

__global__ __launch_bounds__(256) void regulate_kernel(
    const float4* __restrict__ feat,   // (B, T, DD/4)
    const int*    __restrict__ dur,    // (B, T)
    float4*       __restrict__ out)    // (B, MAX_LEN, DD/4)
{
    const int t    = threadIdx.x;
    const int blk  = blockIdx.x & (BPB - 1);   // block within batch
    const int b    = blockIdx.x >> 7;          // batch (BPB = 128)
    const int lane = t & 127;                  // float4 column in 2 KB row
    const int sub  = t >> 7;                   // owns phonemes 2sub, 2sub+1
    const int l    = t & 63;                   // scan lane within wave

    // ---- issue ALL global loads up front (durations first, then rows) ----
    // lane l owns phonemes 8l..8l+7 of this batch for the scan
    const int4* d4p = (const int4*)(dur + b * TT + 8 * l);
    int4 da = d4p[0];
    int4 db = d4p[1];

    // this sub's two feature rows: addresses are STATIC (no scan needed)
    const int ph_a = PPB * blk + 2 * sub;
    const float4* featb = feat + (size_t)b * TT * (DD / 4) + lane;
    float4 va = featb[(size_t)ph_a * (DD / 4)];
    float4 vb = featb[(size_t)(ph_a + 1) * (DD / 4)];

    // ---- wave shfl scan over 512 clamped durations (verified core) ----
    int d[8] = {da.x, da.y, da.z, da.w, db.x, db.y, db.z, db.w};
    int s[8];
    int run = 0;
#pragma unroll
    for (int i = 0; i < 8; ++i) {
        int di = d[i] < 1 ? 1 : d[i];          // clamp(min=1)
        run += di;
        s[i] = run;                            // in-lane inclusive scan
    }
    int incl = run;
#pragma unroll
    for (int off = 1; off < 64; off <<= 1) {
        int v = __shfl_up(incl, off, 64);
        if (l >= off) incl += v;
    }
    const int pre = incl - run;                // exclusive prefix of lane

    // block's 4 phonemes (4blk..4blk+3) live in lane L at i-offset 4*(blk&1)
    const int L = blk >> 1;
    int sm1, sa0, sa1, sa2, sa3;               // s[i0-1], s[i0..i0+3] of lane L
    if (blk & 1) {
        sm1 = __shfl(s[3], L, 64);
        sa0 = __shfl(s[4], L, 64); sa1 = __shfl(s[5], L, 64);
        sa2 = __shfl(s[6], L, 64); sa3 = __shfl(s[7], L, 64);
    } else {
        sm1 = 0;
        sa0 = __shfl(s[0], L, 64); sa1 = __shfl(s[1], L, 64);
        sa2 = __shfl(s[2], L, 64); sa3 = __shfl(s[3], L, 64);
    }
    const int preL  = __shfl(pre, L, 64);
    const int total = __shfl(incl, 63, 64);    // cum[511]

    const int st0 = preL + sm1;                // global start frame of ph 4blk
    const int d0 = sa0 - sm1, d1 = sa1 - sa0, d2 = sa2 - sa1, d3 = sa3 - sa2;

    // ---- store streams: rows x durations, zero loads in the stream ----
    int start, na, nb;
    if (sub == 0) { start = st0;           na = d0; nb = d1; }
    else          { start = st0 + d0 + d1; na = d2; nb = d3; }

    float4* outb = out + (size_t)b * MAX_LEN * (DD / 4) + lane;
    size_t p = (size_t)start * (DD / 4);
    for (int k = 0; k < na; ++k) { outb[p] = va; p += DD / 4; }
    for (int k = 0; k < nb; ++k) { outb[p] = vb; p += DD / 4; }

    // ---- padding [total, MAX_LEN): even slices across the batch's blocks ----
    const int pad = MAX_LEN - total;
    const int q0  = total + ((pad * blk) >> 7);
    const int q1  = total + ((pad * (blk + 1)) >> 7);
    const int h   = q1 - q0;
    const int mid = q0 + ((h + 1) >> 1);
    const int z0  = sub == 0 ? q0 : mid;
    const int z1  = sub == 0 ? mid : q1;
    const float4 zero = make_float4(0.f, 0.f, 0.f, 0.f);
    p = (size_t)z0 * (DD / 4);
    for (int k = z0; k < z1; ++k) { outb[p] = zero; p += DD / 4; }
}

extern "C" void kernel_launch(void* const* d_in, const int* in_sizes, int n_in,
                              void* d_out, int out_size, void* d_ws, size_t ws_size,
                              hipStream_t stream) {
    // Select pointers by element count (features = B*T*D = 2097152, dur = 4096)
    const float* feat;
    const int*   dur;
    if (in_sizes[0] == BB * TT) {
        dur  = (const int*)d_in[0];
        feat = (const float*)d_in[1];
    } else {
        feat = (const float*)d_in[0];
        dur  = (const int*)d_in[1];
    }
    float* out = (float*)d_out;        // (B, MAX_LEN, D) fp32

    regulate_kernel<<<BB * BPB, 256, 0, stream>>>(
        (const float4*)feat, dur, (float4*)out);
}